// Round 7
// baseline (1644.406 us; speedup 1.0000x reference)
//
#include <hip/hip_runtime.h>

typedef unsigned int u32;
typedef unsigned short u16;
typedef u16 u16x8 __attribute__((ext_vector_type(8)));
typedef u16 u16x4 __attribute__((ext_vector_type(4)));
typedef __bf16 bf16x8 __attribute__((ext_vector_type(8)));
typedef __bf16 bf16x4v __attribute__((ext_vector_type(4)));
typedef float f32x4 __attribute__((ext_vector_type(4)));
typedef float f32x2 __attribute__((ext_vector_type(2)));

#define B_SZ 32
#define S_SZ 128
#define T_SZ 127
#define DK 128
#define SKILL 256
#define RL 136   /* hS row pitch (u16): 128 + 8 pad */
#define PP 68    /* part row pitch (f32): 64 + 4 pad */

#define NLOG2E  (-1.44269504f)
#define N2LOG2E (-2.88539008f)

__device__ __forceinline__ u16x4 cvt4(f32x4 v) {
    return __builtin_bit_cast(u16x4, __builtin_convertvector(v, bf16x4v));
}
__device__ __forceinline__ u16x8 cvt8s(f32x4 a, f32x4 b, float s) {
    u16x4 x = cvt4(a * s), y = cvt4(b * s);
    u16x8 r;
    r[0]=x[0]; r[1]=x[1]; r[2]=x[2]; r[3]=x[3];
    r[4]=y[0]; r[5]=y[1]; r[6]=y[2]; r[7]=y[3];
    return r;
}
__device__ __forceinline__ u16 bfu(float x) {
    return __builtin_bit_cast(u16, (__bf16)x);
}
__device__ __forceinline__ f32x4 mfma16(u16x8 a, u16x8 bb, f32x4 c) {
    return __builtin_amdgcn_mfma_f32_16x16x32_bf16(
        __builtin_bit_cast(bf16x8, a), __builtin_bit_cast(bf16x8, bb), c, 0, 0, 0);
}

// ---------------------------------------------------------------------------
// Kernel B (fused le+pre): one (b,t) per block. Outputs PRE-SCALED:
//   PRE_l = -2log2e*(bl + Wl1@le_{t-1} + Wl2@it + Wl3@le_t)
//   PRE_g = -log2e *(bg + Wg1@le_{t-1} + Wg2@it + Wg3@le_t)
//   PRE_f = -log2e *(bf + Wf3@it)
//   PRE_p = -log2e *(bp + Wp1@ex_{t+1})
// ---------------------------------------------------------------------------
__global__ __launch_bounds__(128) void k_pre(
    const int* __restrict__ eid, const int* __restrict__ atime,
    const int* __restrict__ ansv, const int* __restrict__ itime,
    const float* __restrict__ ex_t, const float* __restrict__ at_t,
    const float* __restrict__ it_t,
    const float* __restrict__ W1, const float* __restrict__ b1,
    const float* __restrict__ Wl, const float* __restrict__ blv,
    const float* __restrict__ Wg, const float* __restrict__ bgv,
    const float* __restrict__ Wf, const float* __restrict__ bfv,
    const float* __restrict__ Wp, const float* __restrict__ bpv,
    float* __restrict__ PRE_l, float* __restrict__ PRE_g,
    float* __restrict__ PRE_f, float* __restrict__ PRE_p)
{
    int t = blockIdx.x, b = blockIdx.y, o = threadIdx.x;
    __shared__ float xS[256];
    __shared__ float lp[128], lc[128], itS[128], exN[128];
    const float* wr1 = W1 + o * 384;

    // ---- ex_{t+1} (for PRE_p) ----
    {
        int eN = eid[b * S_SZ + t + 1];
        exN[o] = ex_t[eN * DK + o];
    }
    // ---- le_t -> lc ----
    {
        int e = eid[b * S_SZ + t], a = atime[b * S_SZ + t];
        float av = (float)ansv[b * S_SZ + t];
        xS[o] = ex_t[e * DK + o];
        xS[128 + o] = at_t[a * DK + o];
        __syncthreads();
        float acc = b1[o], wsum = 0.f;
        #pragma unroll 8
        for (int k4 = 0; k4 < 64; ++k4) {
            f32x4 w = *(const f32x4*)(wr1 + 4 * k4);
            acc += w[0] * xS[4 * k4] + w[1] * xS[4 * k4 + 1]
                 + w[2] * xS[4 * k4 + 2] + w[3] * xS[4 * k4 + 3];
        }
        #pragma unroll 8
        for (int k4 = 64; k4 < 96; ++k4) {
            f32x4 w = *(const f32x4*)(wr1 + 4 * k4);
            wsum += w[0] + w[1] + w[2] + w[3];
        }
        lc[o] = acc + av * wsum;
        __syncthreads();
    }
    // ---- le_{t-1} -> lp ----
    if (t > 0) {
        int e = eid[b * S_SZ + t - 1], a = atime[b * S_SZ + t - 1];
        float av = (float)ansv[b * S_SZ + t - 1];
        xS[o] = ex_t[e * DK + o];
        xS[128 + o] = at_t[a * DK + o];
        __syncthreads();
        float acc = b1[o], wsum = 0.f;
        #pragma unroll 8
        for (int k4 = 0; k4 < 64; ++k4) {
            f32x4 w = *(const f32x4*)(wr1 + 4 * k4);
            acc += w[0] * xS[4 * k4] + w[1] * xS[4 * k4 + 1]
                 + w[2] * xS[4 * k4 + 2] + w[3] * xS[4 * k4 + 3];
        }
        #pragma unroll 8
        for (int k4 = 64; k4 < 96; ++k4) {
            f32x4 w = *(const f32x4*)(wr1 + 4 * k4);
            wsum += w[0] + w[1] + w[2] + w[3];
        }
        lp[o] = acc + av * wsum;
    } else {
        lp[o] = 0.f;
    }
    int iv = itime[b * S_SZ + t + 1];
    itS[o] = it_t[iv * DK + o];
    __syncthreads();

    const float* wl = Wl + o * 512;
    const float* wg = Wg + o * 512;
    float al = blv[o], ag = bgv[o];
    #pragma unroll 8
    for (int k4 = 0; k4 < 32; ++k4) {
        f32x4 w  = *(const f32x4*)(wl + 4 * k4);
        f32x4 w2 = *(const f32x4*)(wg + 4 * k4);
        #pragma unroll
        for (int j = 0; j < 4; ++j) {
            float x = lp[4 * k4 + j];
            al += w[j] * x; ag += w2[j] * x;
        }
    }
    #pragma unroll 8
    for (int k4 = 32; k4 < 64; ++k4) {
        f32x4 w  = *(const f32x4*)(wl + 4 * k4);
        f32x4 w2 = *(const f32x4*)(wg + 4 * k4);
        #pragma unroll
        for (int j = 0; j < 4; ++j) {
            float x = itS[4 * k4 - 128 + j];
            al += w[j] * x; ag += w2[j] * x;
        }
    }
    #pragma unroll 8
    for (int k4 = 64; k4 < 96; ++k4) {
        f32x4 w  = *(const f32x4*)(wl + 4 * k4);
        f32x4 w2 = *(const f32x4*)(wg + 4 * k4);
        #pragma unroll
        for (int j = 0; j < 4; ++j) {
            float x = lc[4 * k4 - 256 + j];
            al += w[j] * x; ag += w2[j] * x;
        }
    }
    float af = bfv[o];
    const float* wf = Wf + o * 384 + 256;
    #pragma unroll 8
    for (int k4 = 0; k4 < 32; ++k4) {
        f32x4 w = *(const f32x4*)(wf + 4 * k4);
        af += w[0] * itS[4 * k4] + w[1] * itS[4 * k4 + 1]
            + w[2] * itS[4 * k4 + 2] + w[3] * itS[4 * k4 + 3];
    }
    float ap = bpv[o];
    const float* wp = Wp + o * 256;
    #pragma unroll 8
    for (int k4 = 0; k4 < 32; ++k4) {
        f32x4 w = *(const f32x4*)(wp + 4 * k4);
        ap += w[0] * exN[4 * k4] + w[1] * exN[4 * k4 + 1]
            + w[2] * exN[4 * k4 + 2] + w[3] * exN[4 * k4 + 3];
    }
    size_t idx = (size_t)(b * T_SZ + t) * DK + o;
    PRE_l[idx] = N2LOG2E * al;
    PRE_g[idx] = NLOG2E * ag;
    PRE_f[idx] = NLOG2E * af;
    PRE_p[idx] = NLOG2E * ap;
}

// ---------------------------------------------------------------------------
// Kernel C: sequential scan + fused prediction. 512 threads (8 waves).
// Per step: [pred(t-1) via MFMA on htbf] -> stage PRE(t+1)->LDS, kv(t+2)->regs
//   -> z MFMA ->[B]-> c MFMA ->[C]-> upd1+Zfh2 ->[D]-> upd2+scatter ->[E]->
//   reduce h~ + Zfh1(t+1) ->[TOP]
// PRE loads never sit on the critical path (full-step prefetch distance).
// ---------------------------------------------------------------------------
__global__ __launch_bounds__(512, 1) void k_main(
    const int* __restrict__ eid, const float* __restrict__ qmat,
    const float* __restrict__ Wl, const float* __restrict__ Wg,
    const float* __restrict__ Wf, const float* __restrict__ Wp,
    const float* __restrict__ h0,
    const float* __restrict__ PRE_l, const float* __restrict__ PRE_g,
    const float* __restrict__ PRE_f, const float* __restrict__ PRE_p,
    float* __restrict__ out)
{
    extern __shared__ char smem[];
    u16*   hS   = (u16*)smem;                    // 256*136*2 = 69632
    float* part = (float*)(smem + 69632);        // 128*68*4 -> 104448
    u16*   htbf = (u16*)(smem + 104448);         // hi[128] lo[128] -> 104960
    u16*   LGb  = (u16*)(smem + 104960);         // hi[128] lo[128] -> 105472
    float* LGf  = (float*)(smem + 105472);       // 128 -> 105984
    float* cS   = (float*)(smem + 105984);       // 128 -> 106496
    float* preS = (float*)(smem + 106496);       // [2][512]: pl|pg|pf|pp -> 110592

    const int b    = blockIdx.x;
    const int tid  = threadIdx.x;
    const int w    = tid >> 6;
    const int lane = tid & 63;
    const int quad = lane >> 4;
    const int l4   = lane & 15;
    const int ih   = w & 1;
    const int jh   = w >> 1;

    // ---- persistent A-frags (pre-scaled) ----
    u16x8 afr[4][4];   // Wf1 * -log2e : m = 64ih+16mt+l4
    #pragma unroll
    for (int mt = 0; mt < 4; ++mt)
        #pragma unroll
        for (int kt = 0; kt < 4; ++kt) {
            const float* p = Wf + (64 * ih + 16 * mt + l4) * 384 + 32 * kt + quad * 8;
            afr[mt][kt] = cvt8s(*(const f32x4*)p, *(const f32x4*)(p + 4), NLOG2E);
        }
    u16x8 azf[2][4];   // stacked [Wl4;Wg4] rows rho=32w+16mt+l4
    #pragma unroll
    for (int mt = 0; mt < 2; ++mt) {
        int rho = 32 * w + 16 * mt + l4;
        float sc = (rho & 1) ? NLOG2E : N2LOG2E;
        const float* base = (rho & 1) ? Wg : Wl;
        const float* rp = base + (rho >> 1) * 512 + 384;
        #pragma unroll
        for (int kt = 0; kt < 4; ++kt) {
            const float* p = rp + 32 * kt + quad * 8;
            azf[mt][kt] = cvt8s(*(const f32x4*)p, *(const f32x4*)(p + 4), sc);
        }
    }
    u16x8 acf[4];      // Wf2 * -log2e : m = 16w+l4
    #pragma unroll
    for (int kt = 0; kt < 4; ++kt) {
        const float* p = Wf + (16 * w + l4) * 384 + 128 + 32 * kt + quad * 8;
        acf[kt] = cvt8s(*(const f32x4*)p, *(const f32x4*)(p + 4), NLOG2E);
    }
    u16x8 apf[4];      // Wp2 * -log2e : m = 16w+l4 (pred head)
    #pragma unroll
    for (int kt = 0; kt < 4; ++kt) {
        const float* p = Wp + (16 * w + l4) * 256 + 128 + 32 * kt + quad * 8;
        apf[kt] = cvt8s(*(const f32x4*)p, *(const f32x4*)(p + 4), NLOG2E);
    }

    // ---- h0 -> fp32 regs (C-layout) + bf16 LDS mirror ----
    f32x4 hreg[4][4];   // [mt][nt]
    #pragma unroll
    for (int mt = 0; mt < 4; ++mt) {
        int d0 = 64 * ih + 16 * mt + quad * 4;
        #pragma unroll
        for (int nt = 0; nt < 4; ++nt) {
            int s = 64 * jh + 16 * nt + l4;
            f32x4 hv = *(const f32x4*)(h0 + s * DK + d0);
            hreg[mt][nt] = hv;
            *(u16x4*)(hS + s * RL + d0) = cvt4(hv);
        }
    }
    const int* pE = eid + b * S_SZ;
    float kvt[4], kvn[4];
    #pragma unroll
    for (int nt = 0; nt < 4; ++nt) {
        kvt[nt] = qmat[pE[0] * SKILL + 64 * jh + 16 * nt + l4];
        kvn[nt] = qmat[pE[1] * SKILL + 64 * jh + 16 * nt + l4];
    }
    const float* pPl = PRE_l + (size_t)b * T_SZ * DK;
    const float* pPg = PRE_g + (size_t)b * T_SZ * DK;
    const float* pPf = PRE_f + (size_t)b * T_SZ * DK;
    const float* pPp = PRE_p + (size_t)b * T_SZ * DK;

    // ---- pre-loop stage: buf0 <- pl/pg/pf(0), pp(dummy row 0) ----
    {
        int q = tid >> 7, o = tid & 127;
        const float* src = (q == 0) ? pPl : (q == 1) ? pPg : (q == 2) ? pPf : pPp;
        preS[q * 128 + o] = src[o];
    }

    // ---- h~0 partial scatter ----
    {
        float hp[16];
        #pragma unroll
        for (int v = 0; v < 16; ++v) hp[v] = 0.f;
        #pragma unroll
        for (int nt = 0; nt < 4; ++nt)
            #pragma unroll
            for (int mt = 0; mt < 4; ++mt)
                #pragma unroll
                for (int r = 0; r < 4; ++r)
                    hp[mt * 4 + r] += kvt[nt] * hreg[mt][nt][r];
        #pragma unroll
        for (int mt = 0; mt < 4; ++mt)
            #pragma unroll
            for (int r = 0; r < 4; ++r)
                part[(64 * ih + 16 * mt + quad * 4 + r) * PP + jh * 16 + l4] = hp[mt * 4 + r];
    }
    __syncthreads();
    // ---- h~0 reduce ----
    {
        int d = tid >> 2, kq = tid & 3;
        const float* pp = part + d * PP + kq * 16;
        float v = 0.f;
        #pragma unroll
        for (int i4 = 0; i4 < 4; ++i4) {
            f32x4 x = *(const f32x4*)(pp + 4 * i4);
            v += x[0] + x[1] + x[2] + x[3];
        }
        v += __shfl_xor(v, 1, 64);
        v += __shfl_xor(v, 2, 64);
        if (kq == 0) {
            float hf = (float)(__bf16)v;
            htbf[d] = bfu(v);
            htbf[128 + d] = bfu(v - hf);
        }
    }
    // ---- Zf-h1 for t=0 ----
    f32x4 accF[4][2];
    #pragma unroll
    for (int mt = 0; mt < 4; ++mt)
        #pragma unroll
        for (int n2 = 0; n2 < 2; ++n2)
            accF[mt][n2] = (f32x4){0.f, 0.f, 0.f, 0.f};
    #pragma unroll
    for (int n2 = 0; n2 < 2; ++n2) {
        const u16* bp = hS + (64 * jh + 16 * n2 + l4) * RL + quad * 8;
        #pragma unroll
        for (int kt = 0; kt < 4; ++kt) {
            u16x8 bfr = *(const u16x8*)(bp + kt * 32);
            #pragma unroll
            for (int mt = 0; mt < 4; ++mt)
                accF[mt][n2] = mfma16(afr[mt][kt], bfr, accF[mt][n2]);
        }
    }
    __syncthreads();   // TOP

    for (int t = 0; t <= T_SZ; ++t) {
        const float* bufC = preS + (t & 1) * 512;          // this step's PRE
        // ---- fused prediction for output index t-1 ----
        if (t > 0) {
            f32x4 accP = (f32x4){0.f, 0.f, 0.f, 0.f};
            #pragma unroll
            for (int kt = 0; kt < 4; ++kt) {
                u16x8 bh = *(const u16x8*)(htbf + 32 * kt + quad * 8);
                u16x8 bl = *(const u16x8*)(htbf + 128 + 32 * kt + quad * 8);
                accP = mfma16(apf[kt], bh, accP);
                accP = mfma16(apf[kt], bl, accP);
            }
            if (l4 == 0) {
                f32x4 pp4 = *(const f32x4*)(bufC + 384 + 16 * w + 4 * quad);
                f32x4 pr;
                #pragma unroll
                for (int r = 0; r < 4; ++r) {
                    float e = __builtin_amdgcn_exp2f(accP[r] + pp4[r]);
                    pr[r] = __builtin_amdgcn_rcpf(1.f + e);
                }
                *(f32x4*)(out + (size_t)(b * T_SZ + t - 1) * DK + 16 * w + 4 * quad) = pr;
            }
        }
        if (t == T_SZ) break;

        // ---- stage PRE(t+1) + pp(t) into buf[(t+1)&1]; prefetch kv(t+2) ----
        {
            int q = tid >> 7, o = tid & 127;
            int off = (t + 1 < T_SZ) ? DK : 0;
            const float* src = (q == 0) ? (pPl + off) : (q == 1) ? (pPg + off)
                             : (q == 2) ? (pPf + off) : pPp;
            preS[((t + 1) & 1) * 512 + q * 128 + o] = src[o];
        }
        float kvf[4];
        {
            int ei = pE[(t + 2 <= S_SZ - 1) ? (t + 2) : (S_SZ - 1)];
            #pragma unroll
            for (int nt = 0; nt < 4; ++nt)
                kvf[nt] = qmat[ei * SKILL + 64 * jh + 16 * nt + l4];
        }

        // ---- z MFMA (2 tiles, hi/lo split accumulators) ----
        f32x4 aZh0 = {0.f,0.f,0.f,0.f}, aZl0 = {0.f,0.f,0.f,0.f};
        f32x4 aZh1 = {0.f,0.f,0.f,0.f}, aZl1 = {0.f,0.f,0.f,0.f};
        #pragma unroll
        for (int kt = 0; kt < 4; ++kt) {
            u16x8 bh = *(const u16x8*)(htbf + 32 * kt + quad * 8);
            u16x8 bl = *(const u16x8*)(htbf + 128 + 32 * kt + quad * 8);
            aZh0 = mfma16(azf[0][kt], bh, aZh0);
            aZl0 = mfma16(azf[0][kt], bl, aZl0);
            aZh1 = mfma16(azf[1][kt], bh, aZh1);
            aZl1 = mfma16(azf[1][kt], bl, aZl1);
        }
        if (l4 == 0) {
            #pragma unroll
            for (int mt = 0; mt < 2; ++mt) {
                f32x4 acc = mt ? (aZh1 + aZl1) : (aZh0 + aZl0);
                int d0 = 16 * w + 8 * mt + 2 * quad;
                f32x2 pl2 = *(const f32x2*)(bufC + d0);
                f32x2 pg2 = *(const f32x2*)(bufC + 128 + d0);
                float e0l = __builtin_amdgcn_exp2f(acc[0] + pl2[0]);
                float e0g = __builtin_amdgcn_exp2f(acc[1] + pg2[0]);
                float LG0 = __builtin_amdgcn_rcpf((1.f + e0l) * (1.f + e0g));
                float e1l = __builtin_amdgcn_exp2f(acc[2] + pl2[1]);
                float e1g = __builtin_amdgcn_exp2f(acc[3] + pg2[1]);
                float LG1 = __builtin_amdgcn_rcpf((1.f + e1l) * (1.f + e1g));
                float h0f = (float)(__bf16)LG0;
                float h1f = (float)(__bf16)LG1;
                *(u32*)(LGb + d0) = (u32)bfu(LG0) | ((u32)bfu(LG1) << 16);
                *(u32*)(LGb + 128 + d0) = (u32)bfu(LG0 - h0f) | ((u32)bfu(LG1 - h1f) << 16);
                *(f32x2*)(LGf + d0) = (f32x2){LG0, LG1};
            }
        }
        __syncthreads();   // B: LG ready

        // ---- c MFMA (tile w) ----
        {
            f32x4 aCh = {0.f,0.f,0.f,0.f}, aCl = {0.f,0.f,0.f,0.f};
            #pragma unroll
            for (int kt = 0; kt < 4; ++kt) {
                u16x8 bh = *(const u16x8*)(LGb + 32 * kt + quad * 8);
                u16x8 bl = *(const u16x8*)(LGb + 128 + 32 * kt + quad * 8);
                aCh = mfma16(acf[kt], bh, aCh);
                aCl = mfma16(acf[kt], bl, aCl);
            }
            if (l4 == 0) {
                f32x4 pf = *(const f32x4*)(bufC + 256 + 16 * w + quad * 4);
                *(f32x4*)(cS + 16 * w + quad * 4) = aCh + aCl + pf;
            }
        }
        __syncthreads();   // C: c ready

        // ---- update h1 (nt 0..1) using accF from prev reduce phase ----
        float hp[16];
        #pragma unroll
        for (int v = 0; v < 16; ++v) hp[v] = 0.f;
        #pragma unroll
        for (int mt = 0; mt < 4; ++mt) {
            int d0 = 64 * ih + 16 * mt + quad * 4;
            f32x4 lg = *(const f32x4*)(LGf + d0);
            f32x4 cc = *(const f32x4*)(cS + d0);
            #pragma unroll
            for (int n2 = 0; n2 < 2; ++n2) {
                int s = 64 * jh + 16 * n2 + l4;
                f32x4 hv;
                #pragma unroll
                for (int r = 0; r < 4; ++r) {
                    float e = __builtin_amdgcn_exp2f(accF[mt][n2][r] + cc[r]);
                    float f = __builtin_amdgcn_rcpf(1.f + e);
                    float hn = kvt[n2] * lg[r] + f * hreg[mt][n2][r];
                    hreg[mt][n2][r] = hn;
                    hp[mt * 4 + r] += kvn[n2] * hn;
                    hv[r] = hn;
                }
                *(u16x4*)(hS + s * RL + d0) = cvt4(hv);
            }
        }
        // ---- Zf h2 (rows not yet rewritten this step) ----
        #pragma unroll
        for (int mt = 0; mt < 4; ++mt)
            #pragma unroll
            for (int n2 = 0; n2 < 2; ++n2)
                accF[mt][n2] = (f32x4){0.f, 0.f, 0.f, 0.f};
        #pragma unroll
        for (int n2 = 0; n2 < 2; ++n2) {
            const u16* bp = hS + (64 * jh + 16 * (2 + n2) + l4) * RL + quad * 8;
            #pragma unroll
            for (int kt = 0; kt < 4; ++kt) {
                u16x8 bfr = *(const u16x8*)(bp + kt * 32);
                #pragma unroll
                for (int mt = 0; mt < 4; ++mt)
                    accF[mt][n2] = mfma16(afr[mt][kt], bfr, accF[mt][n2]);
            }
        }
        __syncthreads();   // D: all h2 reads done before h2 writes

        // ---- update h2 (nt 2..3) ----
        #pragma unroll
        for (int mt = 0; mt < 4; ++mt) {
            int d0 = 64 * ih + 16 * mt + quad * 4;
            f32x4 lg = *(const f32x4*)(LGf + d0);
            f32x4 cc = *(const f32x4*)(cS + d0);
            #pragma unroll
            for (int n2 = 0; n2 < 2; ++n2) {
                int nt = 2 + n2;
                int s = 64 * jh + 16 * nt + l4;
                f32x4 hv;
                #pragma unroll
                for (int r = 0; r < 4; ++r) {
                    float e = __builtin_amdgcn_exp2f(accF[mt][n2][r] + cc[r]);
                    float f = __builtin_amdgcn_rcpf(1.f + e);
                    float hn = kvt[nt] * lg[r] + f * hreg[mt][nt][r];
                    hreg[mt][nt][r] = hn;
                    hp[mt * 4 + r] += kvn[nt] * hn;
                    hv[r] = hn;
                }
                *(u16x4*)(hS + s * RL + d0) = cvt4(hv);
            }
        }
        // ---- h~ partial scatter + kv rotate ----
        #pragma unroll
        for (int mt = 0; mt < 4; ++mt)
            #pragma unroll
            for (int r = 0; r < 4; ++r)
                part[(64 * ih + 16 * mt + quad * 4 + r) * PP + jh * 16 + l4] = hp[mt * 4 + r];
        #pragma unroll
        for (int nt = 0; nt < 4; ++nt) { kvt[nt] = kvn[nt]; kvn[nt] = kvf[nt]; }
        __syncthreads();   // E: partials ready, hS final for step t

        // ---- reduce h~ ----
        {
            int d = tid >> 2, kq = tid & 3;
            const float* pp = part + d * PP + kq * 16;
            float v = 0.f;
            #pragma unroll
            for (int i4 = 0; i4 < 4; ++i4) {
                f32x4 x = *(const f32x4*)(pp + 4 * i4);
                v += x[0] + x[1] + x[2] + x[3];
            }
            v += __shfl_xor(v, 1, 64);
            v += __shfl_xor(v, 2, 64);
            if (kq == 0) {
                float hf = (float)(__bf16)v;
                htbf[d] = bfu(v);
                htbf[128 + d] = bfu(v - hf);
            }
        }
        // ---- Zf h1 for t+1 (overlaps reduce) ----
        if (t < T_SZ - 1) {
            #pragma unroll
            for (int mt = 0; mt < 4; ++mt)
                #pragma unroll
                for (int n2 = 0; n2 < 2; ++n2)
                    accF[mt][n2] = (f32x4){0.f, 0.f, 0.f, 0.f};
            #pragma unroll
            for (int n2 = 0; n2 < 2; ++n2) {
                const u16* bp = hS + (64 * jh + 16 * n2 + l4) * RL + quad * 8;
                #pragma unroll
                for (int kt = 0; kt < 4; ++kt) {
                    u16x8 bfr = *(const u16x8*)(bp + kt * 32);
                    #pragma unroll
                    for (int mt = 0; mt < 4; ++mt)
                        accF[mt][n2] = mfma16(afr[mt][kt], bfr, accF[mt][n2]);
                }
            }
        }
        pPl += DK; pPg += DK; pPf += DK; pPp += DK;
        __syncthreads();   // TOP: h~ ready, part/preS consistent
    }
}

extern "C" void kernel_launch(void* const* d_in, const int* in_sizes, int n_in,
                              void* d_out, int out_size, void* d_ws, size_t ws_size,
                              hipStream_t stream) {
    const int* eid     = (const int*)d_in[0];
    const int* atime   = (const int*)d_in[1];
    const int* itime   = (const int*)d_in[2];
    const int* ansv    = (const int*)d_in[3];
    const float* qmat  = (const float*)d_in[4];
    const float* ex_t  = (const float*)d_in[5];
    const float* at_t  = (const float*)d_in[6];
    const float* it_t  = (const float*)d_in[7];
    const float* W1    = (const float*)d_in[8];
    const float* b1    = (const float*)d_in[9];
    const float* Wl    = (const float*)d_in[10];
    const float* blv   = (const float*)d_in[11];
    const float* Wg    = (const float*)d_in[12];
    const float* bgv   = (const float*)d_in[13];
    const float* Wf    = (const float*)d_in[14];
    const float* bfv   = (const float*)d_in[15];
    const float* Wp    = (const float*)d_in[16];
    const float* bpv   = (const float*)d_in[17];
    const float* h0    = (const float*)d_in[18];
    float* out = (float*)d_out;

    const size_t SZ = (size_t)B_SZ * T_SZ * DK;
    float* wsf   = (float*)d_ws;
    float* PRE_l = wsf;
    float* PRE_g = wsf + SZ;
    float* PRE_f = wsf + 2 * SZ;
    float* PRE_p = wsf + 3 * SZ;

    hipFuncSetAttribute((const void*)k_main,
                        hipFuncAttributeMaxDynamicSharedMemorySize, 110592);

    dim3 g(T_SZ, B_SZ);
    k_pre <<<g, 128, 0, stream>>>(eid, atime, ansv, itime, ex_t, at_t, it_t,
                                  W1, b1, Wl, blv, Wg, bgv, Wf, bfv, Wp, bpv,
                                  PRE_l, PRE_g, PRE_f, PRE_p);
    k_main<<<dim3(B_SZ), 512, 110592, stream>>>(eid, qmat, Wl, Wg, Wf, Wp, h0,
                                                PRE_l, PRE_g, PRE_f, PRE_p, out);
}